// Round 7
// baseline (505.018 us; speedup 1.0000x reference)
//
#include <hip/hip_runtime.h>
#include <hip/hip_bf16.h>
#include <cstdint>
#include <cstddef>

#define T_TOK 8192
#define DIM   1024
#define HID   2048
#define NE    8
#define CAP   2816   // 11 tiles of 256; expected count ~2048, +19 sigma margin

#define SLOTSZ 16384  // elems per ring slot (32KB): A[256x32] @0, B[256x32] @8192

typedef __attribute__((ext_vector_type(8))) short bf16x8;
typedef __attribute__((ext_vector_type(4))) float f32x4;
using bf16 = __hip_bfloat16;

__device__ __forceinline__ void gload16(const bf16* g, bf16* l) {
    __builtin_amdgcn_global_load_lds(
        (const __attribute__((address_space(1))) unsigned int*)(g),
        (__attribute__((address_space(3))) unsigned int*)(l), 16, 0, 0);
}
__device__ __forceinline__ float b2f(unsigned short u) {
    return __uint_as_float(((unsigned int)u) << 16);
}
#define MFMA16(a, b, c) __builtin_amdgcn_mfma_f32_16x16x32_bf16((a), (b), (c), 0, 0, 0)
#define BARRIER()  asm volatile("s_barrier" ::: "memory")
#define WAITVM12() asm volatile("s_waitcnt vmcnt(12)" ::: "memory")
#define WAITVM8()  asm volatile("s_waitcnt vmcnt(8)" ::: "memory")
#define WAITVM4()  asm volatile("s_waitcnt vmcnt(4)" ::: "memory")
#define WAITVM0()  asm volatile("s_waitcnt vmcnt(0)" ::: "memory")
#define VMGATE(k, NT) do { \
        int rem_ = (NT) - 1 - (k); \
        if (rem_ >= 3) WAITVM12(); \
        else if (rem_ == 2) WAITVM8(); \
        else if (rem_ == 1) WAITVM4(); \
        else WAITVM0(); } while (0)

// ---- fused per-expert transpose+convert: [E][R][C] f32 -> [E][C][R] bf16 ----
__global__ __launch_bounds__(256) void k_transpose_all(const float* __restrict__ w1,
                                                       const float* __restrict__ w3,
                                                       const float* __restrict__ w2,
                                                       bf16* __restrict__ w1t,
                                                       bf16* __restrict__ w3t,
                                                       bf16* __restrict__ w2t) {
    __shared__ float tile[64][65];
    int z = blockIdx.z;
    const float* in = (z == 0) ? w1 : (z == 1) ? w3 : w2;
    bf16* out = (z == 0) ? w1t : (z == 1) ? w3t : w2t;
    int R = (z == 2) ? HID : DIM;
    int C = (z == 2) ? DIM : HID;
    int e = blockIdx.y;
    int ct = C >> 6;
    int r0 = (blockIdx.x / ct) << 6;
    int c0 = (blockIdx.x % ct) << 6;
    const float* src = in + (size_t)e * R * C;
    bf16* dst = out + (size_t)e * R * C;
    int s = threadIdx.x & 15, g = threadIdx.x >> 4;
#pragma unroll
    for (int j = 0; j < 4; ++j) {
        int row = j * 16 + g;
        float4 v = *(const float4*)(src + (size_t)(r0 + row) * C + c0 + s * 4);
        tile[row][s * 4 + 0] = v.x; tile[row][s * 4 + 1] = v.y;
        tile[row][s * 4 + 2] = v.z; tile[row][s * 4 + 3] = v.w;
    }
    __syncthreads();
#pragma unroll
    for (int j = 0; j < 4; ++j) {
        int c = j * 16 + g;
        int r = s * 4;
        bf16 o[4] = {__float2bfloat16(tile[r][c]),     __float2bfloat16(tile[r + 1][c]),
                     __float2bfloat16(tile[r + 2][c]), __float2bfloat16(tile[r + 3][c])};
        *(uint2*)(dst + (size_t)(c0 + c) * R + r0 + r) = *(const uint2*)o;
    }
}

// ------- router logits (fp64 accum) + x->bf16 conversion fused -------
__global__ __launch_bounds__(256) void k_logits(const float* __restrict__ x,
                                                const float* __restrict__ Wr,
                                                float* __restrict__ logits,
                                                bf16* __restrict__ xb) {
    __shared__ float wl[NE][DIM];
    for (int o = threadIdx.x; o < NE * DIM; o += 256) {
        int e = o >> 10, d = o & (DIM - 1);
        wl[e][d] = Wr[d * NE + e];
    }
    __syncthreads();
    int wid = threadIdx.x >> 6, lane = threadIdx.x & 63;
    int t = blockIdx.x * 4 + wid;
    const float* xr = x + (size_t)t * DIM;
    double acc[NE];
#pragma unroll
    for (int e = 0; e < NE; ++e) acc[e] = 0.0;
#pragma unroll
    for (int i = 0; i < DIM / 256; ++i) {
        int base = i * 256 + lane * 4;
        float4 v = *(const float4*)(xr + base);
        bf16 o[4] = {__float2bfloat16(v.x), __float2bfloat16(v.y),
                     __float2bfloat16(v.z), __float2bfloat16(v.w)};
        *(uint2*)(xb + (size_t)t * DIM + base) = *(const uint2*)o;
#pragma unroll
        for (int e = 0; e < NE; ++e)
            acc[e] += (double)v.x * wl[e][base] + (double)v.y * wl[e][base + 1]
                    + (double)v.z * wl[e][base + 2] + (double)v.w * wl[e][base + 3];
    }
#pragma unroll
    for (int e = 0; e < NE; ++e) {
        double v = acc[e];
        for (int m = 32; m >= 1; m >>= 1) v += __shfl_xor(v, m);
        if (lane == 0) logits[t * NE + e] = (float)v;
    }
}

// ---------------- router: softmax, top-2, segment append ----------------
__global__ __launch_bounds__(256) void k_route(const float* __restrict__ logits,
                                               int* counts, int* seg_tok, float* seg_w,
                                               int* slotpos, float* probsum) {
    int t = blockIdx.x * 256 + threadIdx.x;
    float l[NE];
#pragma unroll
    for (int e = 0; e < NE; ++e) l[e] = logits[t * NE + e];
    float mx = l[0];
#pragma unroll
    for (int e = 1; e < NE; ++e) mx = fmaxf(mx, l[e]);
    float p[NE], s = 0.f;
#pragma unroll
    for (int e = 0; e < NE; ++e) { p[e] = expf(l[e] - mx); s += p[e]; }
    float inv = 1.f / s;
#pragma unroll
    for (int e = 0; e < NE; ++e) p[e] *= inv;
    int e0 = 0; float v0 = p[0];
#pragma unroll
    for (int e = 1; e < NE; ++e) if (p[e] > v0) { v0 = p[e]; e0 = e; }
    int e1 = -1; float v1 = -1.f;
#pragma unroll
    for (int e = 0; e < NE; ++e) if (e != e0 && p[e] > v1) { v1 = p[e]; e1 = e; }
    float wsum = v0 + v1;
    float w0 = v0 / wsum, w1 = v1 / wsum;

    int lane = threadIdx.x & 63, wid = threadIdx.x >> 6;
    __shared__ float ps[4][NE];
#pragma unroll
    for (int e = 0; e < NE; ++e) {
        float v = p[e];
        for (int m = 32; m >= 1; m >>= 1) v += __shfl_xor(v, m);
        if (lane == 0) ps[wid][e] = v;
    }
    __syncthreads();
    if (threadIdx.x < NE) {
        float v = ps[0][threadIdx.x] + ps[1][threadIdx.x] + ps[2][threadIdx.x] + ps[3][threadIdx.x];
        atomicAdd(&probsum[threadIdx.x], v);
    }
    for (int slot = 0; slot < 2; ++slot) {
        int   e  = slot ? e1 : e0;
        float wv = slot ? w1 : w0;
#pragma unroll
        for (int ex = 0; ex < NE; ++ex) {
            unsigned long long m = __ballot(e == ex);
            if (e == ex) {
                int leader = __ffsll(m) - 1;
                int base = 0;
                if (lane == leader) base = atomicAdd(&counts[ex], __popcll(m));
                base = __shfl(base, leader);
                int pos = base + (int)__popcll(m & ((1ull << lane) - 1ull));
                if (pos < CAP) {
                    seg_tok[ex * CAP + pos] = t;
                    seg_w[ex * CAP + pos]  = wv;
                    slotpos[2 * t + slot]  = ex * CAP + pos;
                } else {
                    slotpos[2 * t + slot]  = -1;
                }
            }
        }
    }
}

// ======= GEMM1: BM=256, 128 h-cols (g+u), BK=32, 4-slot ring, 3-deep prefetch =======
// B-panel rows: [0,128) = gate rows, [128,256) = up rows (same 128 h-cols).
// Wave (wm,wn): rows wm*128..+127, h-cols wn*32..+31 -> both g and u fragments.
__global__ __launch_bounds__(512, 1) void k_gemm1(const bf16* __restrict__ xb,
                                                  const bf16* __restrict__ w1t,
                                                  const bf16* __restrict__ w3t,
                                                  const int* __restrict__ counts,
                                                  const int* __restrict__ seg_tok,
                                                  bf16* __restrict__ h) {
    __shared__ __align__(16) bf16 lds[4 * SLOTSZ];
    __shared__ int toks[256];
    const int NTL = HID / 128;                      // 16 ntiles
    int flat = blockIdx.y * gridDim.x + blockIdx.x;
    int cpx  = (gridDim.x * NE) >> 3;               // nwg % 8 == 0
    int swz  = (flat & 7) * cpx + (flat >> 3);
    int e    = swz / gridDim.x;
    int tile = swz % gridDim.x;
    int mtile = tile / NTL, ntile = tile % NTL;
    int cnt = counts[e]; if (cnt > CAP) cnt = CAP;
    if (mtile * 256 >= cnt) return;

    int tx = threadIdx.x, lane = tx & 63, wid = tx >> 6;
    for (int i = tx; i < 256; i += 512) {
        int slot = mtile * 256 + i;
        toks[i] = seg_tok[e * CAP + (slot < cnt ? slot : 0)];
    }
    __syncthreads();

    // stage side: each round = 128 rows x 32k; row = tx>>2, stored chunk = tx&3
    int srow = tx >> 2;
    int sc8  = (((tx & 3) ^ ((tx >> 3) & 3)) << 3); // inverse-swizzled source chunk
    const bf16* sA0 = xb + (size_t)toks[srow]       * DIM + sc8;
    const bf16* sA1 = xb + (size_t)toks[128 + srow] * DIM + sc8;
    const bf16* sBg = w1t + ((size_t)e * HID + ntile * 128 + srow) * DIM + sc8;
    const bf16* sBu = w3t + ((size_t)e * HID + ntile * 128 + srow) * DIM + sc8;

    // read side
    int l15 = lane & 15, lh = lane >> 4;
    int wm = wid >> 2, wn = wid & 3;                // 2M x 4(col-strip)
    int ach = ((lh ^ ((l15 >> 1) & 3)) << 3);
    const int rAoff = (wm * 128 + l15) * 32 + ach;                // + m*512
    const int rBoff = 8192 + (wn * 32 + l15) * 32 + ach;          // g; +4096 -> u

    f32x4 accg[8][2], accu[8][2];
    f32x4 zero4 = {0.f, 0.f, 0.f, 0.f};
#pragma unroll
    for (int m = 0; m < 8; ++m)
#pragma unroll
        for (int n = 0; n < 2; ++n) { accg[m][n] = zero4; accu[m][n] = zero4; }

#define G1_STAGE(s, ko) do { \
        bf16* d_ = lds + (s) * SLOTSZ + tx * 8; \
        gload16(sA0 + (ko), d_); \
        gload16(sA1 + (ko), d_ + 4096); \
        gload16(sBg + (ko), d_ + 8192); \
        gload16(sBu + (ko), d_ + 12288); } while (0)

    G1_STAGE(0, 0); G1_STAGE(1, 32); G1_STAGE(2, 64);
    const int NT = DIM / 32;                        // 32 K-steps
#pragma unroll 1
    for (int k = 0; k < NT; ++k) {
        if (k + 3 < NT) G1_STAGE((k + 3) & 3, (k + 3) * 32);
        VMGATE(k, NT);
        BARRIER();
        const bf16* base = lds + (k & 3) * SLOTSZ;
        bf16x8 a0 = *(const bf16x8*)(base + rAoff);
        bf16x8 a1 = *(const bf16x8*)(base + rAoff + 512);
        bf16x8 a2 = *(const bf16x8*)(base + rAoff + 1024);
        bf16x8 a3 = *(const bf16x8*)(base + rAoff + 1536);
        bf16x8 a4 = *(const bf16x8*)(base + rAoff + 2048);
        bf16x8 a5 = *(const bf16x8*)(base + rAoff + 2560);
        bf16x8 a6 = *(const bf16x8*)(base + rAoff + 3072);
        bf16x8 a7 = *(const bf16x8*)(base + rAoff + 3584);
        bf16x8 g0 = *(const bf16x8*)(base + rBoff);
        bf16x8 g1 = *(const bf16x8*)(base + rBoff + 512);
        bf16x8 u0 = *(const bf16x8*)(base + rBoff + 4096);
        bf16x8 u1 = *(const bf16x8*)(base + rBoff + 4608);
        __builtin_amdgcn_s_setprio(1);
        accg[0][0] = MFMA16(a0, g0, accg[0][0]); accg[1][0] = MFMA16(a1, g0, accg[1][0]);
        accg[2][0] = MFMA16(a2, g0, accg[2][0]); accg[3][0] = MFMA16(a3, g0, accg[3][0]);
        accg[4][0] = MFMA16(a4, g0, accg[4][0]); accg[5][0] = MFMA16(a5, g0, accg[5][0]);
        accg[6][0] = MFMA16(a6, g0, accg[6][0]); accg[7][0] = MFMA16(a7, g0, accg[7][0]);
        accg[0][1] = MFMA16(a0, g1, accg[0][1]); accg[1][1] = MFMA16(a1, g1, accg[1][1]);
        accg[2][1] = MFMA16(a2, g1, accg[2][1]); accg[3][1] = MFMA16(a3, g1, accg[3][1]);
        accg[4][1] = MFMA16(a4, g1, accg[4][1]); accg[5][1] = MFMA16(a5, g1, accg[5][1]);
        accg[6][1] = MFMA16(a6, g1, accg[6][1]); accg[7][1] = MFMA16(a7, g1, accg[7][1]);
        accu[0][0] = MFMA16(a0, u0, accu[0][0]); accu[1][0] = MFMA16(a1, u0, accu[1][0]);
        accu[2][0] = MFMA16(a2, u0, accu[2][0]); accu[3][0] = MFMA16(a3, u0, accu[3][0]);
        accu[4][0] = MFMA16(a4, u0, accu[4][0]); accu[5][0] = MFMA16(a5, u0, accu[5][0]);
        accu[6][0] = MFMA16(a6, u0, accu[6][0]); accu[7][0] = MFMA16(a7, u0, accu[7][0]);
        accu[0][1] = MFMA16(a0, u1, accu[0][1]); accu[1][1] = MFMA16(a1, u1, accu[1][1]);
        accu[2][1] = MFMA16(a2, u1, accu[2][1]); accu[3][1] = MFMA16(a3, u1, accu[3][1]);
        accu[4][1] = MFMA16(a4, u1, accu[4][1]); accu[5][1] = MFMA16(a5, u1, accu[5][1]);
        accu[6][1] = MFMA16(a6, u1, accu[6][1]); accu[7][1] = MFMA16(a7, u1, accu[7][1]);
        __builtin_amdgcn_s_setprio(0);
        BARRIER();
    }
#undef G1_STAGE

    bf16* hdst = h + ((size_t)e * CAP + (size_t)mtile * 256) * HID + ntile * 128;
#pragma unroll
    for (int m = 0; m < 8; ++m)
#pragma unroll
        for (int n = 0; n < 2; ++n)
#pragma unroll
            for (int r = 0; r < 4; ++r) {
                int row = wm * 128 + m * 16 + lh * 4 + r;
                int col = wn * 32 + n * 16 + l15;
                float gg = accg[m][n][r], uu = accu[m][n][r];
                float hv = gg / (1.f + __expf(-gg)) * uu;
                hdst[(size_t)row * HID + col] = __float2bfloat16(hv);
            }
}

// ======= GEMM2: BM=256 x BN=256, BK=32, 4-slot ring, 3-deep prefetch =======
__global__ __launch_bounds__(512, 1) void k_gemm2(const bf16* __restrict__ hbuf,
                                                  const bf16* __restrict__ w2t,
                                                  const int* __restrict__ counts,
                                                  const float* __restrict__ seg_w,
                                                  bf16* __restrict__ ybuf) {
    __shared__ __align__(16) bf16 lds[4 * SLOTSZ];
    __shared__ float wts[256];
    const int NTL = DIM / 256;                      // 4 ntiles
    int flat = blockIdx.y * gridDim.x + blockIdx.x;
    int cpx  = (gridDim.x * NE) >> 3;
    int swz  = (flat & 7) * cpx + (flat >> 3);
    int e    = swz / gridDim.x;
    int tile = swz % gridDim.x;
    int mtile = tile / NTL, ntile = tile % NTL;
    int cnt = counts[e]; if (cnt > CAP) cnt = CAP;
    if (mtile * 256 >= cnt) return;

    int tx = threadIdx.x, lane = tx & 63, wid = tx >> 6;
    for (int i = tx; i < 256; i += 512) {
        int slot = mtile * 256 + i;
        wts[i] = (slot < cnt) ? seg_w[e * CAP + slot] : 0.f;
    }
    __syncthreads();

    int srow = tx >> 2;
    int sc8  = (((tx & 3) ^ ((tx >> 3) & 3)) << 3);
    const bf16* sA0 = hbuf + ((size_t)e * CAP + mtile * 256 + srow) * HID + sc8;
    const bf16* sA1 = hbuf + ((size_t)e * CAP + mtile * 256 + 128 + srow) * HID + sc8;
    const bf16* sB0 = w2t + ((size_t)e * DIM + ntile * 256 + srow) * HID + sc8;
    const bf16* sB1 = w2t + ((size_t)e * DIM + ntile * 256 + 128 + srow) * HID + sc8;

    int l15 = lane & 15, lh = lane >> 4;
    int wm = wid >> 2, wn = wid & 3;
    int ach = ((lh ^ ((l15 >> 1) & 3)) << 3);
    const int rAoff = (wm * 128 + l15) * 32 + ach;
    const int rBoff = 8192 + (wn * 64 + l15) * 32 + ach;

    f32x4 acc[8][4];
    f32x4 zero4 = {0.f, 0.f, 0.f, 0.f};
#pragma unroll
    for (int m = 0; m < 8; ++m)
#pragma unroll
        for (int n = 0; n < 4; ++n) acc[m][n] = zero4;

#define G2_STAGE(s, ko) do { \
        bf16* d_ = lds + (s) * SLOTSZ + tx * 8; \
        gload16(sA0 + (ko), d_); \
        gload16(sA1 + (ko), d_ + 4096); \
        gload16(sB0 + (ko), d_ + 8192); \
        gload16(sB1 + (ko), d_ + 12288); } while (0)

    G2_STAGE(0, 0); G2_STAGE(1, 32); G2_STAGE(2, 64);
    const int NT = HID / 32;                        // 64 K-steps
#pragma unroll 1
    for (int k = 0; k < NT; ++k) {
        if (k + 3 < NT) G2_STAGE((k + 3) & 3, (k + 3) * 32);
        VMGATE(k, NT);
        BARRIER();
        const bf16* base = lds + (k & 3) * SLOTSZ;
        bf16x8 a0 = *(const bf16x8*)(base + rAoff);
        bf16x8 a1 = *(const bf16x8*)(base + rAoff + 512);
        bf16x8 a2 = *(const bf16x8*)(base + rAoff + 1024);
        bf16x8 a3 = *(const bf16x8*)(base + rAoff + 1536);
        bf16x8 a4 = *(const bf16x8*)(base + rAoff + 2048);
        bf16x8 a5 = *(const bf16x8*)(base + rAoff + 2560);
        bf16x8 a6 = *(const bf16x8*)(base + rAoff + 3072);
        bf16x8 a7 = *(const bf16x8*)(base + rAoff + 3584);
        bf16x8 b0 = *(const bf16x8*)(base + rBoff);
        bf16x8 b1 = *(const bf16x8*)(base + rBoff + 512);
        bf16x8 b2 = *(const bf16x8*)(base + rBoff + 1024);
        bf16x8 b3 = *(const bf16x8*)(base + rBoff + 1536);
        __builtin_amdgcn_s_setprio(1);
        acc[0][0] = MFMA16(a0, b0, acc[0][0]); acc[1][0] = MFMA16(a1, b0, acc[1][0]);
        acc[2][0] = MFMA16(a2, b0, acc[2][0]); acc[3][0] = MFMA16(a3, b0, acc[3][0]);
        acc[4][0] = MFMA16(a4, b0, acc[4][0]); acc[5][0] = MFMA16(a5, b0, acc[5][0]);
        acc[6][0] = MFMA16(a6, b0, acc[6][0]); acc[7][0] = MFMA16(a7, b0, acc[7][0]);
        acc[0][1] = MFMA16(a0, b1, acc[0][1]); acc[1][1] = MFMA16(a1, b1, acc[1][1]);
        acc[2][1] = MFMA16(a2, b1, acc[2][1]); acc[3][1] = MFMA16(a3, b1, acc[3][1]);
        acc[4][1] = MFMA16(a4, b1, acc[4][1]); acc[5][1] = MFMA16(a5, b1, acc[5][1]);
        acc[6][1] = MFMA16(a6, b1, acc[6][1]); acc[7][1] = MFMA16(a7, b1, acc[7][1]);
        acc[0][2] = MFMA16(a0, b2, acc[0][2]); acc[1][2] = MFMA16(a1, b2, acc[1][2]);
        acc[2][2] = MFMA16(a2, b2, acc[2][2]); acc[3][2] = MFMA16(a3, b2, acc[3][2]);
        acc[4][2] = MFMA16(a4, b2, acc[4][2]); acc[5][2] = MFMA16(a5, b2, acc[5][2]);
        acc[6][2] = MFMA16(a6, b2, acc[6][2]); acc[7][2] = MFMA16(a7, b2, acc[7][2]);
        acc[0][3] = MFMA16(a0, b3, acc[0][3]); acc[1][3] = MFMA16(a1, b3, acc[1][3]);
        acc[2][3] = MFMA16(a2, b3, acc[2][3]); acc[3][3] = MFMA16(a3, b3, acc[3][3]);
        acc[4][3] = MFMA16(a4, b3, acc[4][3]); acc[5][3] = MFMA16(a5, b3, acc[5][3]);
        acc[6][3] = MFMA16(a6, b3, acc[6][3]); acc[7][3] = MFMA16(a7, b3, acc[7][3]);
        __builtin_amdgcn_s_setprio(0);
        BARRIER();
    }
#undef G2_STAGE

    bf16* ydst = ybuf + ((size_t)e * CAP + (size_t)mtile * 256) * DIM + ntile * 256;
#pragma unroll
    for (int m = 0; m < 8; ++m)
#pragma unroll
        for (int n = 0; n < 4; ++n)
#pragma unroll
            for (int r = 0; r < 4; ++r) {
                int row = wm * 128 + m * 16 + lh * 4 + r;
                int col = wn * 64 + n * 16 + l15;
                ydst[(size_t)row * DIM + col] = __float2bfloat16(acc[m][n][r] * wts[row]);
            }
}

// ---------------- combine: out[t] = ybuf[slot0] + ybuf[slot1] ----------------
__global__ __launch_bounds__(256) void k_combine(const bf16* __restrict__ yb,
                                                 const int* __restrict__ slotpos,
                                                 float* __restrict__ out) {
    int t = blockIdx.x;
    int s0 = slotpos[2 * t], s1 = slotpos[2 * t + 1];
    int d = threadIdx.x * 4;
    float4 a = {0.f, 0.f, 0.f, 0.f};
    if (s0 >= 0) {
        ushort4 v = *(const ushort4*)(yb + (size_t)s0 * DIM + d);
        a.x += b2f(v.x); a.y += b2f(v.y); a.z += b2f(v.z); a.w += b2f(v.w);
    }
    if (s1 >= 0) {
        ushort4 v = *(const ushort4*)(yb + (size_t)s1 * DIM + d);
        a.x += b2f(v.x); a.y += b2f(v.y); a.z += b2f(v.z); a.w += b2f(v.w);
    }
    *(float4*)(out + (size_t)t * DIM + d) = a;
}

// ---------------- aux loss ----------------
__global__ void k_aux(const int* __restrict__ counts, const float* __restrict__ probsum,
                      float* __restrict__ outaux) {
    if (threadIdx.x == 0 && blockIdx.x == 0) {
        float s = 0.f;
        for (int e = 0; e < NE; ++e)
            s += ((float)counts[e] / (float)T_TOK) * (probsum[e] / (float)T_TOK);
        *outaux = (float)NE * s;
    }
}

extern "C" void kernel_launch(void* const* d_in, const int* in_sizes, int n_in,
                              void* d_out, int out_size, void* d_ws, size_t ws_size,
                              hipStream_t stream) {
    const float* x  = (const float*)d_in[0];
    const float* Wr = (const float*)d_in[1];
    const float* w1 = (const float*)d_in[2];
    const float* w2 = (const float*)d_in[3];
    const float* w3 = (const float*)d_in[4];
    float* out = (float*)d_out;

    char* ws = (char*)d_ws;
    size_t off = 0;
    auto alloc = [&](size_t bytes) { void* p = ws + off; off += (bytes + 255) & ~(size_t)255; return p; };
    bf16*  xb      = (bf16*)alloc((size_t)T_TOK * DIM * 2);
    bf16*  w1t     = (bf16*)alloc((size_t)NE * HID * DIM * 2);
    bf16*  w3t     = (bf16*)alloc((size_t)NE * HID * DIM * 2);
    bf16*  w2t     = (bf16*)alloc((size_t)NE * DIM * HID * 2);
    bf16*  hbuf    = (bf16*)alloc((size_t)NE * CAP * HID * 2);
    float* logits  = (float*)alloc((size_t)T_TOK * NE * 4);
    int*   counts  = (int*)alloc(256);
    int*   segtok  = (int*)alloc((size_t)NE * CAP * 4);
    float* segw    = (float*)alloc((size_t)NE * CAP * 4);
    int*   slotpos = (int*)alloc((size_t)T_TOK * 2 * 4);
    float* probsum = (float*)alloc(256);
    // ybuf reuses w1t+w3t (dead after k_gemm1): 46.1 MB < 67.1 MB available
    bf16*  ybuf    = w1t;
    (void)ws_size; (void)in_sizes; (void)n_in;

    hipMemsetAsync(counts, 0, 256, stream);
    hipMemsetAsync(probsum, 0, 256, stream);

    k_logits<<<T_TOK / 4, 256, 0, stream>>>(x, Wr, logits, xb);
    k_route<<<T_TOK / 256, 256, 0, stream>>>(logits, counts, segtok, segw, slotpos, probsum);

    dim3 gt((DIM / 64) * (HID / 64), NE, 3);
    k_transpose_all<<<gt, 256, 0, stream>>>(w1, w3, w2, w1t, w3t, w2t);

    dim3 g1((CAP / 256) * (HID / 128), NE);    // 11*16=176 x 8 = 1408, %8==0
    k_gemm1<<<g1, 512, 0, stream>>>(xb, w1t, w3t, counts, segtok, hbuf);
    dim3 g2((CAP / 256) * (DIM / 256), NE);    // 11*4=44 x 8 = 352, %8==0
    k_gemm2<<<g2, 512, 0, stream>>>(hbuf, w2t, counts, segw, ybuf);

    k_combine<<<T_TOK, 256, 0, stream>>>(ybuf, slotpos, out);
    k_aux<<<1, 64, 0, stream>>>(counts, probsum, out + (size_t)T_TOK * DIM);
}

// Round 8
// 469.977 us; speedup vs baseline: 1.0746x; 1.0746x over previous
//
#include <hip/hip_runtime.h>
#include <hip/hip_bf16.h>
#include <cstdint>
#include <cstddef>

#define T_TOK 8192
#define DIM   1024
#define HID   2048
#define NE    8
#define CAP   2816   // 11 tiles of 256; expected count ~2048, +19 sigma margin

typedef __attribute__((ext_vector_type(8))) short bf16x8;
typedef __attribute__((ext_vector_type(4))) float f32x4;
using bf16 = __hip_bfloat16;

__device__ __forceinline__ void gload16(const bf16* g, bf16* l) {
    __builtin_amdgcn_global_load_lds(
        (const __attribute__((address_space(1))) unsigned int*)(g),
        (__attribute__((address_space(3))) unsigned int*)(l), 16, 0, 0);
}
__device__ __forceinline__ float b2f(unsigned short u) {
    return __uint_as_float(((unsigned int)u) << 16);
}
#define MFMA16(a, b, c) __builtin_amdgcn_mfma_f32_16x16x32_bf16((a), (b), (c), 0, 0, 0)
#define BARRIER()  asm volatile("s_barrier" ::: "memory")
#define WAITVM8()  asm volatile("s_waitcnt vmcnt(8)" ::: "memory")
#define WAITVM0()  asm volatile("s_waitcnt vmcnt(0)" ::: "memory")
#define LGKM0SB()  do { asm volatile("s_waitcnt lgkmcnt(0)" ::: "memory"); \
                        __builtin_amdgcn_sched_barrier(0); } while (0)

// 16-MFMA cluster: rows (MB..MB+3)*16, cols (NB..NB+1)*16, both k-halves
#define QUAD(MB, NB) do { \
    __builtin_amdgcn_s_setprio(1); \
    acc[(MB)+0][(NB)+0] = MFMA16(af[0][0], bfr[(NB)+0][0], acc[(MB)+0][(NB)+0]); \
    acc[(MB)+1][(NB)+0] = MFMA16(af[1][0], bfr[(NB)+0][0], acc[(MB)+1][(NB)+0]); \
    acc[(MB)+2][(NB)+0] = MFMA16(af[2][0], bfr[(NB)+0][0], acc[(MB)+2][(NB)+0]); \
    acc[(MB)+3][(NB)+0] = MFMA16(af[3][0], bfr[(NB)+0][0], acc[(MB)+3][(NB)+0]); \
    acc[(MB)+0][(NB)+1] = MFMA16(af[0][0], bfr[(NB)+1][0], acc[(MB)+0][(NB)+1]); \
    acc[(MB)+1][(NB)+1] = MFMA16(af[1][0], bfr[(NB)+1][0], acc[(MB)+1][(NB)+1]); \
    acc[(MB)+2][(NB)+1] = MFMA16(af[2][0], bfr[(NB)+1][0], acc[(MB)+2][(NB)+1]); \
    acc[(MB)+3][(NB)+1] = MFMA16(af[3][0], bfr[(NB)+1][0], acc[(MB)+3][(NB)+1]); \
    acc[(MB)+0][(NB)+0] = MFMA16(af[0][1], bfr[(NB)+0][1], acc[(MB)+0][(NB)+0]); \
    acc[(MB)+1][(NB)+0] = MFMA16(af[1][1], bfr[(NB)+0][1], acc[(MB)+1][(NB)+0]); \
    acc[(MB)+2][(NB)+0] = MFMA16(af[2][1], bfr[(NB)+0][1], acc[(MB)+2][(NB)+0]); \
    acc[(MB)+3][(NB)+0] = MFMA16(af[3][1], bfr[(NB)+0][1], acc[(MB)+3][(NB)+0]); \
    acc[(MB)+0][(NB)+1] = MFMA16(af[0][1], bfr[(NB)+1][1], acc[(MB)+0][(NB)+1]); \
    acc[(MB)+1][(NB)+1] = MFMA16(af[1][1], bfr[(NB)+1][1], acc[(MB)+1][(NB)+1]); \
    acc[(MB)+2][(NB)+1] = MFMA16(af[2][1], bfr[(NB)+1][1], acc[(MB)+2][(NB)+1]); \
    acc[(MB)+3][(NB)+1] = MFMA16(af[3][1], bfr[(NB)+1][1], acc[(MB)+3][(NB)+1]); \
    __builtin_amdgcn_s_setprio(0); } while (0)

#define RD_A4(mb) do { \
    af[0][0] = *(const bf16x8*)(Ab + ((mb)+0)*1024 + c0sw); \
    af[0][1] = *(const bf16x8*)(Ab + ((mb)+0)*1024 + c1sw); \
    af[1][0] = *(const bf16x8*)(Ab + ((mb)+1)*1024 + c0sw); \
    af[1][1] = *(const bf16x8*)(Ab + ((mb)+1)*1024 + c1sw); \
    af[2][0] = *(const bf16x8*)(Ab + ((mb)+2)*1024 + c0sw); \
    af[2][1] = *(const bf16x8*)(Ab + ((mb)+2)*1024 + c1sw); \
    af[3][0] = *(const bf16x8*)(Ab + ((mb)+3)*1024 + c0sw); \
    af[3][1] = *(const bf16x8*)(Ab + ((mb)+3)*1024 + c1sw); } while (0)
#define RD_B2(nb) do { \
    bfr[(nb)+0][0] = *(const bf16x8*)(Bb + ((nb)+0)*1024 + c0sw); \
    bfr[(nb)+0][1] = *(const bf16x8*)(Bb + ((nb)+0)*1024 + c1sw); \
    bfr[(nb)+1][0] = *(const bf16x8*)(Bb + ((nb)+1)*1024 + c0sw); \
    bfr[(nb)+1][1] = *(const bf16x8*)(Bb + ((nb)+1)*1024 + c1sw); } while (0)

// ---- fused per-expert transpose+convert: [E][R][C] f32 -> [E][C][R] bf16 ----
__global__ __launch_bounds__(256) void k_transpose_all(const float* __restrict__ w1,
                                                       const float* __restrict__ w3,
                                                       const float* __restrict__ w2,
                                                       bf16* __restrict__ w1t,
                                                       bf16* __restrict__ w3t,
                                                       bf16* __restrict__ w2t) {
    __shared__ float tile[64][65];
    int z = blockIdx.z;
    const float* in = (z == 0) ? w1 : (z == 1) ? w3 : w2;
    bf16* out = (z == 0) ? w1t : (z == 1) ? w3t : w2t;
    int R = (z == 2) ? HID : DIM;
    int C = (z == 2) ? DIM : HID;
    int e = blockIdx.y;
    int ct = C >> 6;
    int r0 = (blockIdx.x / ct) << 6;
    int c0 = (blockIdx.x % ct) << 6;
    const float* src = in + (size_t)e * R * C;
    bf16* dst = out + (size_t)e * R * C;
    int s = threadIdx.x & 15, g = threadIdx.x >> 4;
#pragma unroll
    for (int j = 0; j < 4; ++j) {
        int row = j * 16 + g;
        float4 v = *(const float4*)(src + (size_t)(r0 + row) * C + c0 + s * 4);
        tile[row][s * 4 + 0] = v.x; tile[row][s * 4 + 1] = v.y;
        tile[row][s * 4 + 2] = v.z; tile[row][s * 4 + 3] = v.w;
    }
    __syncthreads();
#pragma unroll
    for (int j = 0; j < 4; ++j) {
        int c = j * 16 + g;
        int r = s * 4;
        bf16 o[4] = {__float2bfloat16(tile[r][c]),     __float2bfloat16(tile[r + 1][c]),
                     __float2bfloat16(tile[r + 2][c]), __float2bfloat16(tile[r + 3][c])};
        *(uint2*)(dst + (size_t)(c0 + c) * R + r0 + r) = *(const uint2*)o;
    }
}

// ------- router logits (fp64 accum) + x->bf16 conversion fused -------
__global__ __launch_bounds__(256) void k_logits(const float* __restrict__ x,
                                                const float* __restrict__ Wr,
                                                float* __restrict__ logits,
                                                bf16* __restrict__ xb) {
    __shared__ float wl[NE][DIM];
    for (int o = threadIdx.x; o < NE * DIM; o += 256) {
        int e = o >> 10, d = o & (DIM - 1);
        wl[e][d] = Wr[d * NE + e];
    }
    __syncthreads();
    int wid = threadIdx.x >> 6, lane = threadIdx.x & 63;
    int t = blockIdx.x * 4 + wid;
    const float* xr = x + (size_t)t * DIM;
    double acc[NE];
#pragma unroll
    for (int e = 0; e < NE; ++e) acc[e] = 0.0;
#pragma unroll
    for (int i = 0; i < DIM / 256; ++i) {
        int base = i * 256 + lane * 4;
        float4 v = *(const float4*)(xr + base);
        bf16 o[4] = {__float2bfloat16(v.x), __float2bfloat16(v.y),
                     __float2bfloat16(v.z), __float2bfloat16(v.w)};
        *(uint2*)(xb + (size_t)t * DIM + base) = *(const uint2*)o;
#pragma unroll
        for (int e = 0; e < NE; ++e)
            acc[e] += (double)v.x * wl[e][base] + (double)v.y * wl[e][base + 1]
                    + (double)v.z * wl[e][base + 2] + (double)v.w * wl[e][base + 3];
    }
#pragma unroll
    for (int e = 0; e < NE; ++e) {
        double v = acc[e];
        for (int m = 32; m >= 1; m >>= 1) v += __shfl_xor(v, m);
        if (lane == 0) logits[t * NE + e] = (float)v;
    }
}

// ---------------- router: softmax, top-2, segment append ----------------
__global__ __launch_bounds__(256) void k_route(const float* __restrict__ logits,
                                               int* counts, int* seg_tok, float* seg_w,
                                               int* slotpos, float* probsum) {
    int t = blockIdx.x * 256 + threadIdx.x;
    float l[NE];
#pragma unroll
    for (int e = 0; e < NE; ++e) l[e] = logits[t * NE + e];
    float mx = l[0];
#pragma unroll
    for (int e = 1; e < NE; ++e) mx = fmaxf(mx, l[e]);
    float p[NE], s = 0.f;
#pragma unroll
    for (int e = 0; e < NE; ++e) { p[e] = expf(l[e] - mx); s += p[e]; }
    float inv = 1.f / s;
#pragma unroll
    for (int e = 0; e < NE; ++e) p[e] *= inv;
    int e0 = 0; float v0 = p[0];
#pragma unroll
    for (int e = 1; e < NE; ++e) if (p[e] > v0) { v0 = p[e]; e0 = e; }
    int e1 = -1; float v1 = -1.f;
#pragma unroll
    for (int e = 0; e < NE; ++e) if (e != e0 && p[e] > v1) { v1 = p[e]; e1 = e; }
    float wsum = v0 + v1;
    float w0 = v0 / wsum, w1 = v1 / wsum;

    int lane = threadIdx.x & 63, wid = threadIdx.x >> 6;
    __shared__ float ps[4][NE];
#pragma unroll
    for (int e = 0; e < NE; ++e) {
        float v = p[e];
        for (int m = 32; m >= 1; m >>= 1) v += __shfl_xor(v, m);
        if (lane == 0) ps[wid][e] = v;
    }
    __syncthreads();
    if (threadIdx.x < NE) {
        float v = ps[0][threadIdx.x] + ps[1][threadIdx.x] + ps[2][threadIdx.x] + ps[3][threadIdx.x];
        atomicAdd(&probsum[threadIdx.x], v);
    }
    for (int slot = 0; slot < 2; ++slot) {
        int   e  = slot ? e1 : e0;
        float wv = slot ? w1 : w0;
#pragma unroll
        for (int ex = 0; ex < NE; ++ex) {
            unsigned long long m = __ballot(e == ex);
            if (e == ex) {
                int leader = __ffsll(m) - 1;
                int base = 0;
                if (lane == leader) base = atomicAdd(&counts[ex], __popcll(m));
                base = __shfl(base, leader);
                int pos = base + (int)__popcll(m & ((1ull << lane) - 1ull));
                if (pos < CAP) {
                    seg_tok[ex * CAP + pos] = t;
                    seg_w[ex * CAP + pos]  = wv;
                    slotpos[2 * t + slot]  = ex * CAP + pos;
                } else {
                    slotpos[2 * t + slot]  = -1;
                }
            }
        }
    }
}

// ======= GEMM1: 256 tok x (128g+128u), BK=64, m201 4-phase texture =======
// LDS buf b (32768 elems @ b*32768): A0@0 A1@8192 Bg@16384 Bu@24576 (halves 16KB).
// Half-tile [128 rows][8 chunks of 8]; stored chunk c holds source chunk c^(row&7).
__global__ __launch_bounds__(512, 2) void k_gemm1(const bf16* __restrict__ xb,
                                                  const bf16* __restrict__ w1t,
                                                  const bf16* __restrict__ w3t,
                                                  const int* __restrict__ counts,
                                                  const int* __restrict__ seg_tok,
                                                  bf16* __restrict__ h) {
    __shared__ __align__(16) bf16 lds[65536];
    __shared__ int toks[256];
    const int NTL = HID / 128;                      // 16 ntiles
    int flat = blockIdx.y * gridDim.x + blockIdx.x;
    int cpx  = (gridDim.x * NE) >> 3;
    int swz  = (flat & 7) * cpx + (flat >> 3);
    int e    = swz / gridDim.x;
    int tile = swz % gridDim.x;
    int mtile = tile / NTL, ntile = tile % NTL;
    int cnt = counts[e]; if (cnt > CAP) cnt = CAP;
    if (mtile * 256 >= cnt) return;

    int tx = threadIdx.x, lane = tx & 63, wid = tx >> 6;
    for (int i = tx; i < 256; i += 512) {
        int slot = mtile * 256 + i;
        toks[i] = seg_tok[e * CAP + (slot < cnt ? slot : 0)];
    }
    __syncthreads();

    // stage side
    int srl = tx >> 3;                               // 0..63
    int sch = (((tx & 7) ^ (srl & 7)) << 3);
    const bf16* tA[2][2];
#pragma unroll
    for (int ah = 0; ah < 2; ++ah)
#pragma unroll
        for (int r = 0; r < 2; ++r)
            tA[ah][r] = xb + (size_t)toks[ah * 128 + r * 64 + srl] * DIM + sch;
    const bf16* sBg = w1t + ((size_t)e * HID + ntile * 128 + srl) * DIM + sch;
    const bf16* sBu = w3t + ((size_t)e * HID + ntile * 128 + srl) * DIM + sch;
    bf16* dD = lds + tx * 8;

    // read side
    int l15 = lane & 15, lh = lane >> 4;
    int wm = wid >> 2, wn = wid & 3, hn = wn >> 1, ns = wn & 1;
    int c0sw = ((lh ^ (l15 & 7)) << 3);
    int c1sw = (((4 + lh) ^ (l15 & 7)) << 3);

    f32x4 acc[8][4];
    f32x4 zero4 = {0.f, 0.f, 0.f, 0.f};
#pragma unroll
    for (int m = 0; m < 8; ++m)
#pragma unroll
        for (int n = 0; n < 4; ++n) acc[m][n] = zero4;

#define STG_A1(bo, ah, ko) do { \
        gload16(tA[ah][0] + (ko), dD + (bo) + (ah) * 8192); \
        gload16(tA[ah][1] + (ko), dD + (bo) + (ah) * 8192 + 4096); } while (0)
#define STG_Bg1(bo, ko) do { \
        gload16(sBg + (ko),                      dD + (bo) + 16384); \
        gload16(sBg + (size_t)64 * DIM + (ko),   dD + (bo) + 16384 + 4096); } while (0)
#define STG_Bu1(bo, ko) do { \
        gload16(sBu + (ko),                      dD + (bo) + 24576); \
        gload16(sBu + (size_t)64 * DIM + (ko),   dD + (bo) + 24576 + 4096); } while (0)

    // prologue: tiles 0,1
    STG_A1(0, 0, 0); STG_A1(0, 1, 0); STG_Bg1(0, 0); STG_Bu1(0, 0);
    STG_A1(32768, 0, 64); STG_A1(32768, 1, 64); STG_Bg1(32768, 64); STG_Bu1(32768, 64);
    WAITVM8();
    BARRIER();

    const int NT = DIM / 64;                         // 16 K-tiles
#pragma unroll 1
    for (int t = 0; t < NT; ++t) {
        const int bo = (t & 1) << 15;
        const int ko2 = (t + 2) << 6;
        const bool st = (t + 2 < NT);
        const bf16* Ab = lds + bo + wm * 8192 + l15 * 64;
        const bf16* Bb = lds + bo + 16384 + hn * 8192 + ns * 4096 + l15 * 64;
        bf16x8 af[4][2], bfr[4][2];
        // ---- ph0 ----
        RD_A4(0); RD_B2(0);
        BARRIER(); LGKM0SB();
        QUAD(0, 0);
        BARRIER();
        // ---- ph1 ----
        RD_B2(2);
        BARRIER(); LGKM0SB();
        QUAD(0, 2);
        BARRIER();
        // ---- ph2 ----
        RD_A4(4);
        if (st) { STG_Bg1(bo, ko2); STG_Bu1(bo, ko2); }
        BARRIER(); LGKM0SB();
        QUAD(4, 0);
        BARRIER();
        // ---- ph3 ----
        if (st) { STG_A1(bo, 0, ko2); STG_A1(bo, 1, ko2); }
        BARRIER();
        QUAD(4, 2);
        if (st) WAITVM8(); else WAITVM0();
        BARRIER();
    }
#undef STG_A1
#undef STG_Bg1
#undef STG_Bu1

    // epilogue: u-waves deposit to LDS, g-waves fuse SiLU and store
    if (hn == 1) {
#pragma unroll
        for (int m = 0; m < 8; ++m)
#pragma unroll
            for (int n = 0; n < 4; ++n)
#pragma unroll
                for (int r = 0; r < 4; ++r) {
                    int row = m * 16 + lh * 4 + r;
                    int col = n * 16 + l15;
                    lds[((ns * 2 + wm) * 128 + row) * 64 + col] = __float2bfloat16(acc[m][n][r]);
                }
    }
    __syncthreads();
    if (hn == 0) {
        bf16* hdst = h + ((size_t)e * CAP + (size_t)mtile * 256 + wm * 128) * HID
                       + ntile * 128 + ns * 64;
#pragma unroll
        for (int m = 0; m < 8; ++m)
#pragma unroll
            for (int n = 0; n < 4; ++n)
#pragma unroll
                for (int r = 0; r < 4; ++r) {
                    int row = m * 16 + lh * 4 + r;
                    int col = n * 16 + l15;
                    float gg = acc[m][n][r];
                    float uu = b2f(*(const unsigned short*)&lds[((ns * 2 + wm) * 128 + row) * 64 + col]);
                    float hv = gg / (1.f + __expf(-gg)) * uu;
                    hdst[(size_t)row * HID + col] = __float2bfloat16(hv);
                }
    }
}

// ======= GEMM2: 256 x 256, BK=64, same 4-phase texture; scaled dense store =======
__global__ __launch_bounds__(512, 2) void k_gemm2(const bf16* __restrict__ hbuf,
                                                  const bf16* __restrict__ w2t,
                                                  const int* __restrict__ counts,
                                                  const float* __restrict__ seg_w,
                                                  bf16* __restrict__ ybuf) {
    __shared__ __align__(16) bf16 lds[65536];
    __shared__ float wts[256];
    const int NTL = DIM / 256;                      // 4 ntiles
    int flat = blockIdx.y * gridDim.x + blockIdx.x;
    int cpx  = (gridDim.x * NE) >> 3;
    int swz  = (flat & 7) * cpx + (flat >> 3);
    int e    = swz / gridDim.x;
    int tile = swz % gridDim.x;
    int mtile = tile / NTL, ntile = tile % NTL;
    int cnt = counts[e]; if (cnt > CAP) cnt = CAP;
    if (mtile * 256 >= cnt) return;

    int tx = threadIdx.x, lane = tx & 63, wid = tx >> 6;
    for (int i = tx; i < 256; i += 512) {
        int slot = mtile * 256 + i;
        wts[i] = (slot < cnt) ? seg_w[e * CAP + slot] : 0.f;
    }
    __syncthreads();

    int srl = tx >> 3;
    int sch = (((tx & 7) ^ (srl & 7)) << 3);
    const bf16* sA = hbuf + ((size_t)e * CAP + mtile * 256 + srl) * HID + sch;
    const bf16* sB = w2t  + ((size_t)e * DIM + ntile * 256 + srl) * HID + sch;
    bf16* dD = lds + tx * 8;

    int l15 = lane & 15, lh = lane >> 4;
    int wm = wid >> 2, wn = wid & 3, hn = wn >> 1, ns = wn & 1;
    int c0sw = ((lh ^ (l15 & 7)) << 3);
    int c1sw = (((4 + lh) ^ (l15 & 7)) << 3);

    f32x4 acc[8][4];
    f32x4 zero4 = {0.f, 0.f, 0.f, 0.f};
#pragma unroll
    for (int m = 0; m < 8; ++m)
#pragma unroll
        for (int n = 0; n < 4; ++n) acc[m][n] = zero4;

#define STG_A2(bo, ah, ko) do { \
        gload16(sA + (size_t)((ah) * 128     ) * HID + (ko), dD + (bo) + (ah) * 8192); \
        gload16(sA + (size_t)((ah) * 128 + 64) * HID + (ko), dD + (bo) + (ah) * 8192 + 4096); } while (0)
#define STG_B2(bo, bh, ko) do { \
        gload16(sB + (size_t)((bh) * 128     ) * HID + (ko), dD + (bo) + 16384 + (bh) * 8192); \
        gload16(sB + (size_t)((bh) * 128 + 64) * HID + (ko), dD + (bo) + 16384 + (bh) * 8192 + 4096); } while (0)

    STG_A2(0, 0, 0); STG_A2(0, 1, 0); STG_B2(0, 0, 0); STG_B2(0, 1, 0);
    STG_A2(32768, 0, 64); STG_A2(32768, 1, 64); STG_B2(32768, 0, 64); STG_B2(32768, 1, 64);
    WAITVM8();
    BARRIER();

    const int NT = HID / 64;                         // 32 K-tiles
#pragma unroll 1
    for (int t = 0; t < NT; ++t) {
        const int bo = (t & 1) << 15;
        const int ko2 = (t + 2) << 6;
        const bool st = (t + 2 < NT);
        const bf16* Ab = lds + bo + wm * 8192 + l15 * 64;
        const bf16* Bb = lds + bo + 16384 + hn * 8192 + ns * 4096 + l15 * 64;
        bf16x8 af[4][2], bfr[4][2];
        // ---- ph0 ----
        RD_A4(0); RD_B2(0);
        BARRIER(); LGKM0SB();
        QUAD(0, 0);
        BARRIER();
        // ---- ph1 ----
        RD_B2(2);
        BARRIER(); LGKM0SB();
        QUAD(0, 2);
        BARRIER();
        // ---- ph2 ----
        RD_A4(4);
        if (st) { STG_B2(bo, 0, ko2); STG_B2(bo, 1, ko2); }
        BARRIER(); LGKM0SB();
        QUAD(4, 0);
        BARRIER();
        // ---- ph3 ----
        if (st) { STG_A2(bo, 0, ko2); STG_A2(bo, 1, ko2); }
        BARRIER();
        QUAD(4, 2);
        if (st) WAITVM8(); else WAITVM0();
        BARRIER();
    }
#undef STG_A2
#undef STG_B2

    bf16* ydst = ybuf + ((size_t)e * CAP + (size_t)mtile * 256 + wm * 128) * DIM
                      + ntile * 256 + wn * 64;
#pragma unroll
    for (int m = 0; m < 8; ++m)
#pragma unroll
        for (int n = 0; n < 4; ++n)
#pragma unroll
            for (int r = 0; r < 4; ++r) {
                int row = m * 16 + lh * 4 + r;
                int col = n * 16 + l15;
                ydst[(size_t)row * DIM + col] =
                    __float2bfloat16(acc[m][n][r] * wts[wm * 128 + row]);
            }
}

// ---------------- combine: out[t] = ybuf[slot0] + ybuf[slot1] ----------------
__global__ __launch_bounds__(256) void k_combine(const bf16* __restrict__ yb,
                                                 const int* __restrict__ slotpos,
                                                 float* __restrict__ out) {
    int t = blockIdx.x;
    int s0 = slotpos[2 * t], s1 = slotpos[2 * t + 1];
    int d = threadIdx.x * 4;
    float4 a = {0.f, 0.f, 0.f, 0.f};
    if (s0 >= 0) {
        ushort4 v = *(const ushort4*)(yb + (size_t)s0 * DIM + d);
        a.x += b2f(v.x); a.y += b2f(v.y); a.z += b2f(v.z); a.w += b2f(v.w);
    }
    if (s1 >= 0) {
        ushort4 v = *(const ushort4*)(yb + (size_t)s1 * DIM + d);
        a.x += b2f(v.x); a.y += b2f(v.y); a.z += b2f(v.z); a.w += b2f(v.w);
    }
    *(float4*)(out + (size_t)t * DIM + d) = a;
}

// ---------------- aux loss ----------------
__global__ void k_aux(const int* __restrict__ counts, const float* __restrict__ probsum,
                      float* __restrict__ outaux) {
    if (threadIdx.x == 0 && blockIdx.x == 0) {
        float s = 0.f;
        for (int e = 0; e < NE; ++e)
            s += ((float)counts[e] / (float)T_TOK) * (probsum[e] / (float)T_TOK);
        *outaux = (float)NE * s;
    }
}

extern "C" void kernel_launch(void* const* d_in, const int* in_sizes, int n_in,
                              void* d_out, int out_size, void* d_ws, size_t ws_size,
                              hipStream_t stream) {
    const float* x  = (const float*)d_in[0];
    const float* Wr = (const float*)d_in[1];
    const float* w1 = (const float*)d_in[2];
    const float* w2 = (const float*)d_in[3];
    const float* w3 = (const float*)d_in[4];
    float* out = (float*)d_out;

    char* ws = (char*)d_ws;
    size_t off = 0;
    auto alloc = [&](size_t bytes) { void* p = ws + off; off += (bytes + 255) & ~(size_t)255; return p; };
    bf16*  xb      = (bf16*)alloc((size_t)T_TOK * DIM * 2);
    bf16*  w1t     = (bf16*)alloc((size_t)NE * HID * DIM * 2);
    bf16*  w3t     = (bf16*)alloc((size_t)NE * HID * DIM * 2);
    bf16*  w2t     = (bf16*)alloc((size_t)NE * DIM * HID * 2);
    bf16*  hbuf    = (bf16*)alloc((size_t)NE * CAP * HID * 2);
    float* logits  = (float*)alloc((size_t)T_TOK * NE * 4);
    int*   counts  = (int*)alloc(256);
    int*   segtok  = (int*)alloc((size_t)NE * CAP * 4);
    float* segw    = (float*)alloc((size_t)NE * CAP * 4);
    int*   slotpos = (int*)alloc((size_t)T_TOK * 2 * 4);
    float* probsum = (float*)alloc(256);
    // ybuf reuses w1t+w3t (dead after k_gemm1): 46.1 MB < 67.1 MB available
    bf16*  ybuf    = w1t;
    (void)ws_size; (void)in_sizes; (void)n_in;

    hipMemsetAsync(counts, 0, 256, stream);
    hipMemsetAsync(probsum, 0, 256, stream);

    k_logits<<<T_TOK / 4, 256, 0, stream>>>(x, Wr, logits, xb);
    k_route<<<T_TOK / 256, 256, 0, stream>>>(logits, counts, segtok, segw, slotpos, probsum);

    dim3 gt((DIM / 64) * (HID / 64), NE, 3);
    k_transpose_all<<<gt, 256, 0, stream>>>(w1, w3, w2, w1t, w3t, w2t);

    dim3 g1((CAP / 256) * (HID / 128), NE);    // 176 x 8 = 1408, %8==0
    k_gemm1<<<g1, 512, 0, stream>>>(xb, w1t, w3t, counts, segtok, hbuf);
    dim3 g2((CAP / 256) * (DIM / 256), NE);    // 44 x 8 = 352, %8==0
    k_gemm2<<<g2, 512, 0, stream>>>(hbuf, w2t, counts, segw, ybuf);

    k_combine<<<T_TOK, 256, 0, stream>>>(ybuf, slotpos, out);
    k_aux<<<1, 64, 0, stream>>>(counts, probsum, out + (size_t)T_TOK * DIM);
}

// Round 10
// 387.583 us; speedup vs baseline: 1.3030x; 1.2126x over previous
//
#include <hip/hip_runtime.h>
#include <hip/hip_bf16.h>
#include <cstdint>
#include <cstddef>

#define T_TOK 8192
#define DIM   1024
#define HID   2048
#define NE    8
#define CAP   2816   // 22 tiles of 128; expected count ~2048, +19 sigma margin

typedef __attribute__((ext_vector_type(8))) short bf16x8;
typedef __attribute__((ext_vector_type(4))) float f32x4;
using bf16 = __hip_bfloat16;

__device__ __forceinline__ void gload16(const bf16* g, bf16* l) {
    __builtin_amdgcn_global_load_lds(
        (const __attribute__((address_space(1))) unsigned int*)(g),
        (__attribute__((address_space(3))) unsigned int*)(l), 16, 0, 0);
}
__device__ __forceinline__ float b2f(unsigned short u) {
    return __uint_as_float(((unsigned int)u) << 16);
}
#define MFMA16(a, b, c) __builtin_amdgcn_mfma_f32_16x16x32_bf16((a), (b), (c), 0, 0, 0)

// ---- fused per-expert transpose+convert: [E][R][C] f32 -> [E][C][R] bf16 ----
__global__ __launch_bounds__(256) void k_transpose_all(const float* __restrict__ w1,
                                                       const float* __restrict__ w3,
                                                       const float* __restrict__ w2,
                                                       bf16* __restrict__ w1t,
                                                       bf16* __restrict__ w3t,
                                                       bf16* __restrict__ w2t) {
    __shared__ float tile[64][65];
    int z = blockIdx.z;
    const float* in = (z == 0) ? w1 : (z == 1) ? w3 : w2;
    bf16* out = (z == 0) ? w1t : (z == 1) ? w3t : w2t;
    int R = (z == 2) ? HID : DIM;
    int C = (z == 2) ? DIM : HID;
    int e = blockIdx.y;
    int ct = C >> 6;
    int r0 = (blockIdx.x / ct) << 6;
    int c0 = (blockIdx.x % ct) << 6;
    const float* src = in + (size_t)e * R * C;
    bf16* dst = out + (size_t)e * R * C;
    int s = threadIdx.x & 15, g = threadIdx.x >> 4;
#pragma unroll
    for (int j = 0; j < 4; ++j) {
        int row = j * 16 + g;
        float4 v = *(const float4*)(src + (size_t)(r0 + row) * C + c0 + s * 4);
        tile[row][s * 4 + 0] = v.x; tile[row][s * 4 + 1] = v.y;
        tile[row][s * 4 + 2] = v.z; tile[row][s * 4 + 3] = v.w;
    }
    __syncthreads();
#pragma unroll
    for (int j = 0; j < 4; ++j) {
        int c = j * 16 + g;
        int r = s * 4;
        bf16 o[4] = {__float2bfloat16(tile[r][c]),     __float2bfloat16(tile[r + 1][c]),
                     __float2bfloat16(tile[r + 2][c]), __float2bfloat16(tile[r + 3][c])};
        *(uint2*)(dst + (size_t)(c0 + c) * R + r0 + r) = *(const uint2*)o;
    }
}

// ------- router logits (fp64 accum) + x->bf16 conversion fused -------
__global__ __launch_bounds__(256) void k_logits(const float* __restrict__ x,
                                                const float* __restrict__ Wr,
                                                float* __restrict__ logits,
                                                bf16* __restrict__ xb) {
    __shared__ float wl[NE][DIM];
    for (int o = threadIdx.x; o < NE * DIM; o += 256) {
        int e = o >> 10, d = o & (DIM - 1);
        wl[e][d] = Wr[d * NE + e];
    }
    __syncthreads();
    int wid = threadIdx.x >> 6, lane = threadIdx.x & 63;
    int t = blockIdx.x * 4 + wid;
    const float* xr = x + (size_t)t * DIM;
    double acc[NE];
#pragma unroll
    for (int e = 0; e < NE; ++e) acc[e] = 0.0;
#pragma unroll
    for (int i = 0; i < DIM / 256; ++i) {
        int base = i * 256 + lane * 4;
        float4 v = *(const float4*)(xr + base);
        bf16 o[4] = {__float2bfloat16(v.x), __float2bfloat16(v.y),
                     __float2bfloat16(v.z), __float2bfloat16(v.w)};
        *(uint2*)(xb + (size_t)t * DIM + base) = *(const uint2*)o;
#pragma unroll
        for (int e = 0; e < NE; ++e)
            acc[e] += (double)v.x * wl[e][base] + (double)v.y * wl[e][base + 1]
                    + (double)v.z * wl[e][base + 2] + (double)v.w * wl[e][base + 3];
    }
#pragma unroll
    for (int e = 0; e < NE; ++e) {
        double v = acc[e];
        for (int m = 32; m >= 1; m >>= 1) v += __shfl_xor(v, m);
        if (lane == 0) logits[t * NE + e] = (float)v;
    }
}

// ---------------- router: softmax, top-2, segment append ----------------
__global__ __launch_bounds__(256) void k_route(const float* __restrict__ logits,
                                               int* counts, int* seg_tok, float* seg_w,
                                               int* slotpos, float* probsum) {
    int t = blockIdx.x * 256 + threadIdx.x;
    float l[NE];
#pragma unroll
    for (int e = 0; e < NE; ++e) l[e] = logits[t * NE + e];
    float mx = l[0];
#pragma unroll
    for (int e = 1; e < NE; ++e) mx = fmaxf(mx, l[e]);
    float p[NE], s = 0.f;
#pragma unroll
    for (int e = 0; e < NE; ++e) { p[e] = expf(l[e] - mx); s += p[e]; }
    float inv = 1.f / s;
#pragma unroll
    for (int e = 0; e < NE; ++e) p[e] *= inv;
    int e0 = 0; float v0 = p[0];
#pragma unroll
    for (int e = 1; e < NE; ++e) if (p[e] > v0) { v0 = p[e]; e0 = e; }
    int e1 = -1; float v1 = -1.f;
#pragma unroll
    for (int e = 0; e < NE; ++e) if (e != e0 && p[e] > v1) { v1 = p[e]; e1 = e; }
    float wsum = v0 + v1;
    float w0 = v0 / wsum, w1 = v1 / wsum;

    int lane = threadIdx.x & 63, wid = threadIdx.x >> 6;
    __shared__ float ps[4][NE];
#pragma unroll
    for (int e = 0; e < NE; ++e) {
        float v = p[e];
        for (int m = 32; m >= 1; m >>= 1) v += __shfl_xor(v, m);
        if (lane == 0) ps[wid][e] = v;
    }
    __syncthreads();
    if (threadIdx.x < NE) {
        float v = ps[0][threadIdx.x] + ps[1][threadIdx.x] + ps[2][threadIdx.x] + ps[3][threadIdx.x];
        atomicAdd(&probsum[threadIdx.x], v);
    }
    for (int slot = 0; slot < 2; ++slot) {
        int   e  = slot ? e1 : e0;
        float wv = slot ? w1 : w0;
#pragma unroll
        for (int ex = 0; ex < NE; ++ex) {
            unsigned long long m = __ballot(e == ex);
            if (e == ex) {
                int leader = __ffsll(m) - 1;
                int base = 0;
                if (lane == leader) base = atomicAdd(&counts[ex], __popcll(m));
                base = __shfl(base, leader);
                int pos = base + (int)__popcll(m & ((1ull << lane) - 1ull));
                if (pos < CAP) {
                    seg_tok[ex * CAP + pos] = t;
                    seg_w[ex * CAP + pos]  = wv;
                    slotpos[2 * t + slot]  = ex * CAP + pos;
                } else {
                    slotpos[2 * t + slot]  = -1;
                }
            }
        }
    }
}

// ======= GEMM1 (m97-clone): 128 tok x 64 h (g+u), BK=64, single-buffer 32KB =======
// LDS elems: A[128][64] @0, Bg[64][64] @8192, Bu[64][64] @12288.
// Row r at r*64; stored chunk c of row r holds source chunk c^(r&7).
// One gload16 = 512 elems = 8 rows; lane l -> row base+ (l>>3), chunk (l&7).
__global__ __launch_bounds__(256, 3) void k_gemm1(const bf16* __restrict__ xb,
                                                  const bf16* __restrict__ w1t,
                                                  const bf16* __restrict__ w3t,
                                                  const int* __restrict__ counts,
                                                  const int* __restrict__ seg_tok,
                                                  bf16* __restrict__ h) {
    __shared__ __align__(16) bf16 lds[16384];
    __shared__ int toks[128];
    const int NTL = HID / 64;                       // 32 ntiles (ntile-fast: A L2 reuse)
    int flat = blockIdx.y * gridDim.x + blockIdx.x;
    int cpx  = (gridDim.x * NE) >> 3;               // nwg % 8 == 0
    int swz  = (flat & 7) * cpx + (flat >> 3);
    int e    = swz / gridDim.x;
    int tile = swz % gridDim.x;
    int mtile = tile / NTL, ntile = tile % NTL;
    int cnt = counts[e]; if (cnt > CAP) cnt = CAP;
    if (mtile * 128 >= cnt) return;

    int tx = threadIdx.x, lane = tx & 63, w = tx >> 6;
    if (tx < 128) {
        int slot = mtile * 128 + tx;
        toks[tx] = seg_tok[e * CAP + (slot < cnt ? slot : 0)];
    }
    __syncthreads();

    // ---- stage-side addressing ----
    int l8 = lane >> 3;                              // row within 8-row stripe
    int sch = (((lane & 7) ^ l8) << 3);              // pre-swizzled source chunk
    const bf16* sA[4];                               // A rows w*32 + i*8 + l8
#pragma unroll
    for (int i = 0; i < 4; ++i)
        sA[i] = xb + (size_t)toks[w * 32 + i * 8 + l8] * DIM + sch;
    const bf16* sBg[2];                              // B rows w*16 + j*8 + l8
    const bf16* sBu[2];
#pragma unroll
    for (int j = 0; j < 2; ++j) {
        int br = ntile * 64 + w * 16 + j * 8 + l8;
        sBg[j] = w1t + ((size_t)e * HID + br) * DIM + sch;
        sBu[j] = w3t + ((size_t)e * HID + br) * DIM + sch;
    }
    bf16* dA  = lds + w * 2048 + (lane << 3);            // + i*512
    bf16* dBg = lds + 8192  + w * 1024 + (lane << 3);    // + j*512
    bf16* dBu = lds + 12288 + w * 1024 + (lane << 3);    // + j*512

    // ---- read-side addressing ----
    int l15 = lane & 15, lh = lane >> 4;
    int wm = w >> 1, wn = w & 1;                     // wave = 64 rows x 32 h-cols
    f32x4 accg[4][2], accu[4][2];
    f32x4 zero4 = {0.f, 0.f, 0.f, 0.f};
#pragma unroll
    for (int m = 0; m < 4; ++m)
#pragma unroll
        for (int n = 0; n < 2; ++n) { accg[m][n] = zero4; accu[m][n] = zero4; }

    const int NT = DIM / 64;                         // 16 K-iters
#pragma unroll 1
    for (int k = 0; k < NT; ++k) {
        int ko = k * 64;
#pragma unroll
        for (int i = 0; i < 4; ++i) gload16(sA[i] + ko, dA + i * 512);
#pragma unroll
        for (int j = 0; j < 2; ++j) {
            gload16(sBg[j] + ko, dBg + j * 512);
            gload16(sBu[j] + ko, dBu + j * 512);
        }
        __syncthreads();
#pragma unroll
        for (int ks = 0; ks < 2; ++ks) {
            int co = ((((ks << 2) | lh) ^ (l15 & 7)) << 3);
            bf16x8 af[4], bg[2], bu[2];
#pragma unroll
            for (int m = 0; m < 4; ++m) {
                int row = wm * 64 + m * 16 + l15;
                af[m] = *(const bf16x8*)(lds + row * 64 + co);
            }
#pragma unroll
            for (int n = 0; n < 2; ++n) {
                int br = wn * 32 + n * 16 + l15;
                bg[n] = *(const bf16x8*)(lds + 8192 + br * 64 + co);
                bu[n] = *(const bf16x8*)(lds + 12288 + br * 64 + co);
            }
#pragma unroll
            for (int n = 0; n < 2; ++n)
#pragma unroll
                for (int m = 0; m < 4; ++m) {
                    accg[m][n] = MFMA16(af[m], bg[n], accg[m][n]);
                    accu[m][n] = MFMA16(af[m], bu[n], accu[m][n]);
                }
        }
        __syncthreads();
    }

    bf16* hdst = h + ((size_t)e * CAP + (size_t)mtile * 128) * HID + ntile * 64;
#pragma unroll
    for (int m = 0; m < 4; ++m)
#pragma unroll
        for (int n = 0; n < 2; ++n)
#pragma unroll
            for (int r = 0; r < 4; ++r) {
                int row = wm * 64 + m * 16 + lh * 4 + r;
                int col = wn * 32 + n * 16 + l15;
                float gg = accg[m][n][r], uu = accu[m][n][r];
                float hv = gg / (1.f + __expf(-gg)) * uu;
                hdst[(size_t)row * HID + col] = __float2bfloat16(hv);
            }
}

// ======= GEMM2 (m97-clone): 128 x 128, BK=64, single-buffer 32KB; scaled store =======
// LDS elems: A[128][64] @0, B[128][64] @8192.
__global__ __launch_bounds__(256, 3) void k_gemm2(const bf16* __restrict__ hbuf,
                                                  const bf16* __restrict__ w2t,
                                                  const int* __restrict__ counts,
                                                  const float* __restrict__ seg_w,
                                                  bf16* __restrict__ ybuf) {
    __shared__ __align__(16) bf16 lds[16384];
    __shared__ float wts[128];
    const int NTL = DIM / 128;                      // 8 ntiles
    int flat = blockIdx.y * gridDim.x + blockIdx.x;
    int cpx  = (gridDim.x * NE) >> 3;
    int swz  = (flat & 7) * cpx + (flat >> 3);
    int e    = swz / gridDim.x;
    int tile = swz % gridDim.x;
    int mtile = tile / NTL, ntile = tile % NTL;
    int cnt = counts[e]; if (cnt > CAP) cnt = CAP;
    if (mtile * 128 >= cnt) return;

    int tx = threadIdx.x, lane = tx & 63, w = tx >> 6;
    if (tx < 128) {
        int slot = mtile * 128 + tx;
        wts[tx] = (slot < cnt) ? seg_w[e * CAP + slot] : 0.f;
    }
    __syncthreads();

    int l8 = lane >> 3;
    int sch = (((lane & 7) ^ l8) << 3);
    const bf16* sA[4];
    const bf16* sB[4];
#pragma unroll
    for (int i = 0; i < 4; ++i) {
        sA[i] = hbuf + ((size_t)e * CAP + mtile * 128 + w * 32 + i * 8 + l8) * HID + sch;
        sB[i] = w2t + ((size_t)e * DIM + ntile * 128 + w * 32 + i * 8 + l8) * HID + sch;
    }
    bf16* dA = lds + w * 2048 + (lane << 3);             // + i*512
    bf16* dB = lds + 8192 + w * 2048 + (lane << 3);      // + i*512

    int l15 = lane & 15, lh = lane >> 4;
    int wm = w >> 1, wn = w & 1;                     // wave = 64 x 64
    f32x4 acc[4][4];
    f32x4 zero4 = {0.f, 0.f, 0.f, 0.f};
#pragma unroll
    for (int m = 0; m < 4; ++m)
#pragma unroll
        for (int n = 0; n < 4; ++n) acc[m][n] = zero4;

    const int NT = HID / 64;                         // 32 K-iters
#pragma unroll 1
    for (int k = 0; k < NT; ++k) {
        int ko = k * 64;
#pragma unroll
        for (int i = 0; i < 4; ++i) {
            gload16(sA[i] + ko, dA + i * 512);
            gload16(sB[i] + ko, dB + i * 512);
        }
        __syncthreads();
#pragma unroll
        for (int ks = 0; ks < 2; ++ks) {
            int co = ((((ks << 2) | lh) ^ (l15 & 7)) << 3);
            bf16x8 af[4], bf_[4];
#pragma unroll
            for (int m = 0; m < 4; ++m) {
                int row = wm * 64 + m * 16 + l15;
                af[m] = *(const bf16x8*)(lds + row * 64 + co);
                int br = wn * 64 + m * 16 + l15;
                bf_[m] = *(const bf16x8*)(lds + 8192 + br * 64 + co);
            }
#pragma unroll
            for (int n = 0; n < 4; ++n)
#pragma unroll
                for (int m = 0; m < 4; ++m)
                    acc[m][n] = MFMA16(af[m], bf_[n], acc[m][n]);
        }
        __syncthreads();
    }

    bf16* ydst = ybuf + ((size_t)e * CAP + (size_t)mtile * 128) * DIM + ntile * 128;
#pragma unroll
    for (int m = 0; m < 4; ++m)
#pragma unroll
        for (int n = 0; n < 4; ++n)
#pragma unroll
            for (int r = 0; r < 4; ++r) {
                int row = wm * 64 + m * 16 + lh * 4 + r;
                int col = wn * 64 + n * 16 + l15;
                ydst[(size_t)row * DIM + col] = __float2bfloat16(acc[m][n][r] * wts[row]);
            }
}

// ---------------- combine: out[t] = ybuf[slot0] + ybuf[slot1] ----------------
__global__ __launch_bounds__(256) void k_combine(const bf16* __restrict__ yb,
                                                 const int* __restrict__ slotpos,
                                                 float* __restrict__ out) {
    int t = blockIdx.x;
    int s0 = slotpos[2 * t], s1 = slotpos[2 * t + 1];
    int d = threadIdx.x * 4;
    float4 a = {0.f, 0.f, 0.f, 0.f};
    if (s0 >= 0) {
        ushort4 v = *(const ushort4*)(yb + (size_t)s0 * DIM + d);
        a.x += b2f(v.x); a.y += b2f(v.y); a.z += b2f(v.z); a.w += b2f(v.w);
    }
    if (s1 >= 0) {
        ushort4 v = *(const ushort4*)(yb + (size_t)s1 * DIM + d);
        a.x += b2f(v.x); a.y += b2f(v.y); a.z += b2f(v.z); a.w += b2f(v.w);
    }
    *(float4*)(out + (size_t)t * DIM + d) = a;
}

// ---------------- aux loss ----------------
__global__ void k_aux(const int* __restrict__ counts, const float* __restrict__ probsum,
                      float* __restrict__ outaux) {
    if (threadIdx.x == 0 && blockIdx.x == 0) {
        float s = 0.f;
        for (int e = 0; e < NE; ++e)
            s += ((float)counts[e] / (float)T_TOK) * (probsum[e] / (float)T_TOK);
        *outaux = (float)NE * s;
    }
}

extern "C" void kernel_launch(void* const* d_in, const int* in_sizes, int n_in,
                              void* d_out, int out_size, void* d_ws, size_t ws_size,
                              hipStream_t stream) {
    const float* x  = (const float*)d_in[0];
    const float* Wr = (const float*)d_in[1];
    const float* w1 = (const float*)d_in[2];
    const float* w2 = (const float*)d_in[3];
    const float* w3 = (const float*)d_in[4];
    float* out = (float*)d_out;

    char* ws = (char*)d_ws;
    size_t off = 0;
    auto alloc = [&](size_t bytes) { void* p = ws + off; off += (bytes + 255) & ~(size_t)255; return p; };
    bf16*  xb      = (bf16*)alloc((size_t)T_TOK * DIM * 2);
    bf16*  w1t     = (bf16*)alloc((size_t)NE * HID * DIM * 2);
    bf16*  w3t     = (bf16*)alloc((size_t)NE * HID * DIM * 2);
    bf16*  w2t     = (bf16*)alloc((size_t)NE * DIM * HID * 2);
    bf16*  hbuf    = (bf16*)alloc((size_t)NE * CAP * HID * 2);
    float* logits  = (float*)alloc((size_t)T_TOK * NE * 4);
    int*   counts  = (int*)alloc(256);
    int*   segtok  = (int*)alloc((size_t)NE * CAP * 4);
    float* segw    = (float*)alloc((size_t)NE * CAP * 4);
    int*   slotpos = (int*)alloc((size_t)T_TOK * 2 * 4);
    float* probsum = (float*)alloc(256);
    // ybuf reuses w1t+w3t (dead after k_gemm1): 46.1 MB < 67.1 MB available
    bf16*  ybuf    = w1t;
    (void)ws_size; (void)in_sizes; (void)n_in;

    hipMemsetAsync(counts, 0, 256, stream);
    hipMemsetAsync(probsum, 0, 256, stream);

    k_logits<<<T_TOK / 4, 256, 0, stream>>>(x, Wr, logits, xb);
    k_route<<<T_TOK / 256, 256, 0, stream>>>(logits, counts, segtok, segw, slotpos, probsum);

    dim3 gt((DIM / 64) * (HID / 64), NE, 3);
    k_transpose_all<<<gt, 256, 0, stream>>>(w1, w3, w2, w1t, w3t, w2t);

    dim3 g1((CAP / 128) * (HID / 64), NE);     // 22*32=704 x 8 = 5632, %8==0
    k_gemm1<<<g1, 256, 0, stream>>>(xb, w1t, w3t, counts, segtok, hbuf);
    dim3 g2((CAP / 128) * (DIM / 128), NE);    // 22*8=176 x 8 = 1408, %8==0
    k_gemm2<<<g2, 256, 0, stream>>>(hbuf, w2t, counts, segw, ybuf);

    k_combine<<<T_TOK, 256, 0, stream>>>(ybuf, slotpos, out);
    k_aux<<<1, 64, 0, stream>>>(counts, probsum, out + (size_t)T_TOK * DIM);
}